// Round 3
// baseline (114.133 us; speedup 1.0000x reference)
//
#include <hip/hip_runtime.h>
#include <hip/hip_bf16.h>

#define LWAV   480000
#define XPADL  481024
#define NBATCH 32
#define TOUT   1000
#define NFFT   1024
#define NBINS  513
#define NMEL   64
#define PWC    512
#define SPECW  1024
#define HOP    480

// workspace layout (bytes), 256-aligned
#define XPAD_OFF 0u           // 32*481024*2   = 30,785,536
#define WB_OFF   30785536u    // 1026*1024*2   =  2,101,248
#define WMT_OFF  32886784u    // 64*512*2      =     65,536
#define PW_OFF   32952320u    // 32000*512*2   = 32,768,000
#define LM_OFF   65720320u    // 32000*64*4    =  8,192,000  -> end 73,912,320

typedef __attribute__((ext_vector_type(8))) __bf16 bf16x8;
typedef __attribute__((ext_vector_type(8))) unsigned short ushort8;
typedef __attribute__((ext_vector_type(4))) float  f32x4;

__device__ __forceinline__ void gload16(const void* g, void* l) {
  __builtin_amdgcn_global_load_lds((const __attribute__((address_space(1))) void*)g,
                                   (__attribute__((address_space(3))) void*)l, 16, 0, 0);
}

#define WAIT_VM(n) asm volatile("s_waitcnt vmcnt(" #n ")" ::: "memory")
#define BAR() __builtin_amdgcn_s_barrier()

// ---------------- prepass ----------------
#define NV1 (NBATCH * (XPADL / 8))          // 1,924,096
#define NV2 ((1026 * NFFT) / 8)             //   131,328
#define NV3 ((NMEL * PWC) / 8)              //     4,096

__global__ void prep_kernel(const float* __restrict__ wav,
                            const float* __restrict__ wstft,
                            const float* __restrict__ mf,
                            unsigned char* __restrict__ ws) {
  __hip_bfloat16* xpad = (__hip_bfloat16*)(ws + XPAD_OFF);
  __hip_bfloat16* wb   = (__hip_bfloat16*)(ws + WB_OFF);
  __hip_bfloat16* wmt  = (__hip_bfloat16*)(ws + WMT_OFF);
  int idx = blockIdx.x * blockDim.x + threadIdx.x;
  if (idx < NV1) {
    int b  = idx / (XPADL / 8);
    int pg = (idx - b * (XPADL / 8)) * 8;
    __hip_bfloat16* dst = xpad + (size_t)b * XPADL + pg;
    const float* src = wav + (size_t)b * LWAV;
    if (pg >= 512 && pg <= LWAV + 496) {
      float4 v0 = *(const float4*)(src + pg - 512);
      float4 v1 = *(const float4*)(src + pg - 508);
      __hip_bfloat16 t[8];
      t[0] = __float2bfloat16(v0.x); t[1] = __float2bfloat16(v0.y);
      t[2] = __float2bfloat16(v0.z); t[3] = __float2bfloat16(v0.w);
      t[4] = __float2bfloat16(v1.x); t[5] = __float2bfloat16(v1.y);
      t[6] = __float2bfloat16(v1.z); t[7] = __float2bfloat16(v1.w);
      *(uint4*)dst = *(const uint4*)t;
    } else {
      for (int j = 0; j < 8; ++j) {
        int s = pg + j - 512;
        if (s < 0) s = -s;
        else if (s >= LWAV) s = 2 * (LWAV - 1) - s;
        dst[j] = __float2bfloat16(src[s]);
      }
    }
  } else if (idx < NV1 + NV2) {
    int g = (idx - NV1) * 8;
    float4 v0 = *(const float4*)(wstft + g);
    float4 v1 = *(const float4*)(wstft + g + 4);
    __hip_bfloat16 t[8];
    t[0] = __float2bfloat16(v0.x); t[1] = __float2bfloat16(v0.y);
    t[2] = __float2bfloat16(v0.z); t[3] = __float2bfloat16(v0.w);
    t[4] = __float2bfloat16(v1.x); t[5] = __float2bfloat16(v1.y);
    t[6] = __float2bfloat16(v1.z); t[7] = __float2bfloat16(v1.w);
    *(uint4*)(wb + g) = *(const uint4*)t;
  } else if (idx < NV1 + NV2 + NV3) {
    int j  = idx - NV1 - NV2;
    int n  = j / (PWC / 8);
    int k0 = (j - n * (PWC / 8)) * 8;
    for (int k = k0; k < k0 + 8; ++k)
      wmt[n * PWC + k] = __float2bfloat16(mf[k * NMEL + n]);
  }
}

// ---------------- STFT: 256x256 8-phase counted-vmcnt MFMA GEMM + power epilogue ----
// BM=256 frames, BN=256 weight rows = 128 bins x {cos,sin} interleaved per 16-row
// group: tile row n -> bin = bin0 + (n>>5)*16 + (n&15), part = (n>>4)&1.
// 8 waves (2M x 4N), BK=64, 16 K-tiles, dbuf LDS 128 KiB, stages in 64-row
// "quarters" (2 gload16/thread/phase), vmcnt(6) at phases 4 & 8 only.
#define STFT_NWG 500
__launch_bounds__(512, 2)
__global__ void stft_kernel(unsigned char* __restrict__ ws) {
  __shared__ __align__(16) unsigned char lds[131072];  // A0,A1 @0/32768; B0,B1 @65536/98304
  const unsigned char* xpadb = ws + XPAD_OFF;
  const unsigned char* wbb   = ws + WB_OFF;
  __hip_bfloat16* pw = (__hip_bfloat16*)(ws + PW_OFF);

  const int tid  = threadIdx.x;
  const int lane = tid & 63;
  const int w    = tid >> 6;     // wave 0..7
  const int wm   = w >> 2;       // 0..1  (m-half)
  const int wc   = w & 3;        // 0..3  (n-quad)

  // bijective XCD-chunked swizzle (nwg=500: q=62, r=4), n-tile fastest
  const int orig = blockIdx.x;
  const int q8 = STFT_NWG / 8, r8 = STFT_NWG % 8;
  const int xcd = orig & 7;
  const int wg = (xcd < r8 ? xcd * (q8 + 1) : r8 * (q8 + 1) + (xcd - r8) * q8) + (orig >> 3);
  const int bin0 = (wg & 3) * 128;
  const int m0   = (wg >> 2) * 256;

  const int srow = tid >> 3;          // 0..63 (row within quarter)
  const int scol = (tid & 7) << 4;    // byte col 0..112

  // global source bases (pre-swizzled column per T2/rule-21)
  const unsigned char *gA0, *gA1, *gA2, *gA3, *gB0, *gB1, *gB2, *gB3;
  {
    int r0 = srow, r1 = 64 + srow, r2 = 128 + srow, r3 = 192 + srow;
    int m, bb, tt;
    m = m0 + r0; bb = m / 1000; tt = m - bb * 1000;
    gA0 = xpadb + ((size_t)bb * XPADL + (size_t)tt * HOP) * 2 + (scol ^ ((r0 & 7) << 4));
    m = m0 + r1; bb = m / 1000; tt = m - bb * 1000;
    gA1 = xpadb + ((size_t)bb * XPADL + (size_t)tt * HOP) * 2 + (scol ^ ((r1 & 7) << 4));
    m = m0 + r2; bb = m / 1000; tt = m - bb * 1000;
    gA2 = xpadb + ((size_t)bb * XPADL + (size_t)tt * HOP) * 2 + (scol ^ ((r2 & 7) << 4));
    m = m0 + r3; bb = m / 1000; tt = m - bb * 1000;
    gA3 = xpadb + ((size_t)bb * XPADL + (size_t)tt * HOP) * 2 + (scol ^ ((r3 & 7) << 4));
#define BROW(r) ((size_t)(bin0 + (((r) >> 5) << 4) + ((r) & 15) + ((((r) >> 4) & 1) * 513)) * 2048)
    gB0 = wbb + BROW(r0) + (scol ^ ((r0 & 7) << 4));
    gB1 = wbb + BROW(r1) + (scol ^ ((r1 & 7) << 4));
    gB2 = wbb + BROW(r2) + (scol ^ ((r2 & 7) << 4));
    gB3 = wbb + BROW(r3) + (scol ^ ((r3 & 7) << 4));
  }

#define LDSA(c, qq) ((void*)(lds + (c) * 32768 + (qq) * 8192 + w * 1024))
#define LDSB(c, qq) ((void*)(lds + 65536 + (c) * 32768 + (qq) * 8192 + w * 1024))
#define STG_B01(c, kb) do { gload16(gB0 + (kb), LDSB(c, 0)); gload16(gB1 + (kb), LDSB(c, 1)); } while (0)
#define STG_B23(c, kb) do { gload16(gB2 + (kb), LDSB(c, 2)); gload16(gB3 + (kb), LDSB(c, 3)); } while (0)
#define STG_A02(c, kb) do { gload16(gA0 + (kb), LDSA(c, 0)); gload16(gA2 + (kb), LDSA(c, 2)); } while (0)
#define STG_A13(c, kb) do { gload16(gA1 + (kb), LDSA(c, 1)); gload16(gA3 + (kb), LDSA(c, 3)); } while (0)

  f32x4 acc[8][4];
#pragma unroll
  for (int a = 0; a < 8; ++a)
#pragma unroll
    for (int b = 0; b < 4; ++b) acc[a][b] = (f32x4){0.f, 0.f, 0.f, 0.f};

  // prologue: k0 fully (8 loads) + k1 B+Aq02 (6 loads); retire k0, leave 6 in flight
  STG_B01(0, 0); STG_B23(0, 0); STG_A02(0, 0); STG_A13(0, 0);
  STG_B01(1, 128); STG_B23(1, 128); STG_A02(1, 128);
  WAIT_VM(6);
  BAR();

  bf16x8 bfr[4][2];
  bf16x8 af[2][2];

  for (int i = 0; i < 8; ++i) {
    const int kbO  = i * 256 + 128;   // odd ktile 2i+1 (A13 stage @ ph0)
    const int kbN  = i * 256 + 256;   // next even ktile 2i+2
    const int kbN1 = i * 256 + 384;   // next odd  ktile 2i+3
#pragma unroll
    for (int ph = 0; ph < 8; ++ph) {
      const int cc = ph >> 2;         // consuming buffer
      const int qq = ph & 3;          // m-quadrant
      const unsigned char* bA = lds + cc * 32768;
      const unsigned char* bB = lds + 65536 + cc * 32768;
      if (qq == 0) {
#pragma unroll
        for (int nf = 0; nf < 4; ++nf)
#pragma unroll
          for (int ks = 0; ks < 2; ++ks) {
            int row = wc * 64 + nf * 16 + (lane & 15);
            bfr[nf][ks] = *(const bf16x8*)(bB + row * 128 +
                            ((ks * 64 + ((lane >> 4) << 4)) ^ ((row & 7) << 4)));
          }
      }
#pragma unroll
      for (int mi = 0; mi < 2; ++mi)
#pragma unroll
        for (int ks = 0; ks < 2; ++ks) {
          int row = wm * 128 + (qq * 2 + mi) * 16 + (lane & 15);
          af[mi][ks] = *(const bf16x8*)(bA + row * 128 +
                          ((ks * 64 + ((lane >> 4) << 4)) ^ ((row & 7) << 4)));
        }
      // staging rotation (quarter-death-safe; see schedule derivation)
      if (ph == 0) { STG_A13(1, kbO); }
      if (i < 7) {
        if (ph == 1) STG_B01(0, kbN);
        if (ph == 2) STG_B23(0, kbN);
        if (ph == 3) STG_A02(0, kbN);
        if (ph == 4) STG_A13(0, kbN);
        if (ph == 5) STG_B01(1, kbN1);
        if (ph == 6) STG_B23(1, kbN1);
        if (ph == 7) STG_A02(1, kbN1);
      }
      if (ph == 3) { if (i < 7) { WAIT_VM(6); } else { WAIT_VM(0); } }
      if (ph == 7 && i < 7) { WAIT_VM(6); }
      BAR();
      __builtin_amdgcn_s_setprio(1);
#pragma unroll
      for (int mi = 0; mi < 2; ++mi)
#pragma unroll
        for (int nf = 0; nf < 4; ++nf) {
          acc[qq * 2 + mi][nf] = __builtin_amdgcn_mfma_f32_16x16x32_bf16(
              af[mi][0], bfr[nf][0], acc[qq * 2 + mi][nf], 0, 0, 0);
          acc[qq * 2 + mi][nf] = __builtin_amdgcn_mfma_f32_16x16x32_bf16(
              af[mi][1], bfr[nf][1], acc[qq * 2 + mi][nf], 0, 0, 0);
        }
      __builtin_amdgcn_s_setprio(0);
      BAR();
    }
  }

  // epilogue: power = cos^2 + sin^2 (frag pairs (0,1),(2,3) within each wave)
  const int col = lane & 15;
  const int rg  = lane >> 4;
#pragma unroll
  for (int mf_ = 0; mf_ < 8; ++mf_)
#pragma unroll
    for (int g = 0; g < 2; ++g) {
      int bin = bin0 + wc * 32 + g * 16 + col;
#pragma unroll
      for (int rr = 0; rr < 4; ++rr) {
        int m = m0 + wm * 128 + mf_ * 16 + rg * 4 + rr;
        float c = acc[mf_][2 * g][rr];
        float s = acc[mf_][2 * g + 1][rr];
        pw[(size_t)m * PWC + bin] = __float2bfloat16(c * c + s * s);
      }
    }
}

// ---------------- mel GEMM (K=512) + fused bin-512 rank-1 + log10 ----------------
__launch_bounds__(256, 2)
__global__ void mel_kernel(unsigned char* __restrict__ ws, const float* __restrict__ mfp) {
  __shared__ __align__(16) unsigned char sA[128 * 128];
  __shared__ __align__(16) unsigned char sBt[64 * 128];
  __shared__ __align__(16) __hip_bfloat16 wrow[2][1024];
  __shared__ float p512s[128];
  const unsigned char* xpadb = ws + XPAD_OFF;
  const unsigned char* wbb   = ws + WB_OFF;
  const unsigned char* pwb   = ws + PW_OFF;
  const unsigned char* wmtb  = ws + WMT_OFF;
  float* lm = (float*)(ws + LM_OFF);

  const int tid = threadIdx.x;
  const int lane = tid & 63;
  const int wid  = tid >> 6;
  const int m0 = blockIdx.x * 128;

  // stage w512 cos/sin rows (wb rows 512 / 1025)
  {
    int rsel = tid >> 7;
    int seg  = (tid & 127) * 16;
    *(uint4*)((unsigned char*)wrow + rsel * 2048 + seg) =
        *(const uint4*)(wbb + (size_t)(rsel ? 1025 : 512) * 2048 + seg);
  }
  __syncthreads();
  // per-thread full dot: thread (mloc=tid>>1, part=tid&1)
  {
    int mloc = tid >> 1, part = tid & 1;
    int m = m0 + mloc, bb = m / 1000, tt = m - bb * 1000;
    const unsigned char* fb = xpadb + ((size_t)bb * XPADL + (size_t)tt * HOP) * 2;
    float dot = 0.f;
    for (int j = 0; j < 128; ++j) {
      ushort8 fv = *(const ushort8*)(fb + j * 16);
      ushort8 wv = *(const ushort8*)((const unsigned char*)wrow + part * 2048 + j * 16);
#pragma unroll
      for (int e = 0; e < 8; ++e)
        dot += __uint_as_float((unsigned)fv[e] << 16) * __uint_as_float((unsigned)wv[e] << 16);
    }
    float od = __shfl_xor(dot, 1);
    if (part == 0) p512s[mloc] = dot * dot + od * od;
  }

  const int srow = lane >> 3;
  const int kb2  = (lane & 7) << 4;

  const unsigned char* aptr[4];
  unsigned char* aldst[4];
#pragma unroll
  for (int j = 0; j < 4; ++j) {
    int rr = wid * 32 + j * 8 + srow;
    aptr[j] = pwb + (size_t)(m0 + rr) * (PWC * 2) + (kb2 ^ ((rr & 7) << 4));
    aldst[j] = &sA[(wid * 32 + j * 8) * 128];
  }
  const unsigned char* bptr[2];
  unsigned char* bldst[2];
#pragma unroll
  for (int j = 0; j < 2; ++j) {
    int rr = wid * 16 + j * 8 + srow;
    bptr[j] = wmtb + (size_t)rr * (PWC * 2) + (kb2 ^ ((rr & 7) << 4));
    bldst[j] = &sBt[(wid * 16 + j * 8) * 128];
  }

  f32x4 acc[2][4];
#pragma unroll
  for (int mi = 0; mi < 2; ++mi)
#pragma unroll
    for (int fr = 0; fr < 4; ++fr) acc[mi][fr] = (f32x4){0.f, 0.f, 0.f, 0.f};

  for (int kk = 0; kk < PWC; kk += 64) {
    __syncthreads();
#pragma unroll
    for (int j = 0; j < 4; ++j) gload16(aptr[j] + (size_t)kk * 2, aldst[j]);
#pragma unroll
    for (int j = 0; j < 2; ++j) gload16(bptr[j] + (size_t)kk * 2, bldst[j]);
    __syncthreads();
#pragma unroll
    for (int ks = 0; ks < 2; ++ks) {
      const int kby = ks * 64 + ((lane >> 4) << 4);
      bf16x8 af[2], bfr[4];
#pragma unroll
      for (int mi = 0; mi < 2; ++mi) {
        int rr = wid * 32 + mi * 16 + (lane & 15);
        af[mi] = *(const bf16x8*)&sA[rr * 128 + (kby ^ ((rr & 7) << 4))];
      }
#pragma unroll
      for (int fr = 0; fr < 4; ++fr) {
        int rr = fr * 16 + (lane & 15);
        bfr[fr] = *(const bf16x8*)&sBt[rr * 128 + (kby ^ ((rr & 7) << 4))];
      }
#pragma unroll
      for (int mi = 0; mi < 2; ++mi)
#pragma unroll
        for (int fr = 0; fr < 4; ++fr)
          acc[mi][fr] = __builtin_amdgcn_mfma_f32_16x16x32_bf16(af[mi], bfr[fr], acc[mi][fr], 0, 0, 0);
    }
  }

  const int col = lane & 15;
  const int rg  = lane >> 4;
#pragma unroll
  for (int mi = 0; mi < 2; ++mi)
#pragma unroll
    for (int fr = 0; fr < 4; ++fr) {
      int n = fr * 16 + col;
      float f512 = mfp[512 * NMEL + n];
#pragma unroll
      for (int rr = 0; rr < 4; ++rr) {
        int mrow = wid * 32 + mi * 16 + rg * 4 + rr;
        float v = acc[mi][fr][rr] + p512s[mrow] * f512;
        lm[(size_t)(m0 + mrow) * NMEL + n] = 10.0f * log10f(fmaxf(v, 1e-10f));
      }
    }
}

// ---------------- bilinear (time-axis only) interp ----------------
__global__ void interp_kernel(const unsigned char* __restrict__ ws, float* __restrict__ out) {
  const float* lm = (const float*)(ws + LM_OFF);
  int idx = blockIdx.x * blockDim.x + threadIdx.x;
  if (idx >= NBATCH * SPECW * 16) return;
  int m4 = idx & 15;
  int h  = (idx >> 4) & (SPECW - 1);
  int b  = idx >> 14;
  const float scale = (float)(999.0 / 1023.0);
  float pos = (float)h * scale;
  int i0 = (int)floorf(pos);
  if (i0 > TOUT - 1) i0 = TOUT - 1;
  float w = pos - (float)i0;
  int i1 = i0 + 1;
  if (i1 > TOUT - 1) i1 = TOUT - 1;
  const float4* r0 = (const float4*)(lm + ((size_t)b * TOUT + i0) * NMEL);
  const float4* r1 = (const float4*)(lm + ((size_t)b * TOUT + i1) * NMEL);
  float4 a = r0[m4], c = r1[m4];
  float4 o;
  o.x = a.x * (1.0f - w) + c.x * w;
  o.y = a.y * (1.0f - w) + c.y * w;
  o.z = a.z * (1.0f - w) + c.z * w;
  o.w = a.w * (1.0f - w) + c.w * w;
  ((float4*)out)[idx] = o;
}

extern "C" void kernel_launch(void* const* d_in, const int* in_sizes, int n_in,
                              void* d_out, int out_size, void* d_ws, size_t ws_size,
                              hipStream_t stream) {
  (void)in_sizes; (void)n_in; (void)out_size; (void)ws_size;
  const float* wav   = (const float*)d_in[0];
  const float* wstft = (const float*)d_in[1];
  const float* mf    = (const float*)d_in[2];
  unsigned char* ws  = (unsigned char*)d_ws;
  float* out = (float*)d_out;

  const int tot = NV1 + NV2 + NV3;
  prep_kernel<<<(tot + 255) / 256, 256, 0, stream>>>(wav, wstft, mf, ws);
  stft_kernel<<<STFT_NWG, 512, 0, stream>>>(ws);
  mel_kernel<<<250, 256, 0, stream>>>(ws, mf);
  interp_kernel<<<(NBATCH * SPECW * 16) / 256, 256, 0, stream>>>(ws, out);
}

// Round 4
// 112.724 us; speedup vs baseline: 1.0125x; 1.0125x over previous
//
#include <hip/hip_runtime.h>
#include <hip/hip_bf16.h>

#define LWAV   480000
#define XPADL  481024
#define NBATCH 32
#define TOUT   1000
#define NFFT   1024
#define NBINS  513
#define NMEL   64
#define PWC    512
#define SPECW  1024
#define HOP    480

// workspace layout (bytes), 256-aligned
#define XPAD_OFF 0u           // 32*481024*2   = 30,785,536
#define WB_OFF   30785536u    // 1026*1024*2   =  2,101,248
#define WMT_OFF  32886784u    // 64*512*2      =     65,536
#define PW_OFF   32952320u    // 32000*512*2   = 32,768,000
#define LM_OFF   65720320u    // 32000*64*4    =  8,192,000
#define P512_OFF 73912320u    // 32000*4       =    128,000  -> end 74,040,320

typedef __attribute__((ext_vector_type(8))) __bf16 bf16x8;
typedef __attribute__((ext_vector_type(8))) unsigned short ushort8;
typedef __attribute__((ext_vector_type(4))) float  f32x4;

__device__ __forceinline__ void gload16(const void* g, void* l) {
  __builtin_amdgcn_global_load_lds((const __attribute__((address_space(1))) void*)g,
                                   (__attribute__((address_space(3))) void*)l, 16, 0, 0);
}

#define WAIT_VM(n) asm volatile("s_waitcnt vmcnt(" #n ")" ::: "memory")
#define BAR() __builtin_amdgcn_s_barrier()

__device__ __forceinline__ float bf2f(unsigned short u) {
  return __uint_as_float((unsigned)u << 16);
}

// ---------------- prepass ----------------
#define NV1 (NBATCH * (XPADL / 8))          // 1,924,096
#define NV2 ((1026 * NFFT) / 8)             //   131,328
#define NV3 ((NMEL * PWC) / 8)              //     4,096

__global__ void prep_kernel(const float* __restrict__ wav,
                            const float* __restrict__ wstft,
                            const float* __restrict__ mf,
                            unsigned char* __restrict__ ws) {
  __hip_bfloat16* xpad = (__hip_bfloat16*)(ws + XPAD_OFF);
  __hip_bfloat16* wb   = (__hip_bfloat16*)(ws + WB_OFF);
  __hip_bfloat16* wmt  = (__hip_bfloat16*)(ws + WMT_OFF);
  int idx = blockIdx.x * blockDim.x + threadIdx.x;
  if (idx < NV1) {
    int b  = idx / (XPADL / 8);
    int pg = (idx - b * (XPADL / 8)) * 8;
    __hip_bfloat16* dst = xpad + (size_t)b * XPADL + pg;
    const float* src = wav + (size_t)b * LWAV;
    if (pg >= 512 && pg <= LWAV + 496) {
      float4 v0 = *(const float4*)(src + pg - 512);
      float4 v1 = *(const float4*)(src + pg - 508);
      __hip_bfloat16 t[8];
      t[0] = __float2bfloat16(v0.x); t[1] = __float2bfloat16(v0.y);
      t[2] = __float2bfloat16(v0.z); t[3] = __float2bfloat16(v0.w);
      t[4] = __float2bfloat16(v1.x); t[5] = __float2bfloat16(v1.y);
      t[6] = __float2bfloat16(v1.z); t[7] = __float2bfloat16(v1.w);
      *(uint4*)dst = *(const uint4*)t;
    } else {
      for (int j = 0; j < 8; ++j) {
        int s = pg + j - 512;
        if (s < 0) s = -s;
        else if (s >= LWAV) s = 2 * (LWAV - 1) - s;
        dst[j] = __float2bfloat16(src[s]);
      }
    }
  } else if (idx < NV1 + NV2) {
    int g = (idx - NV1) * 8;
    float4 v0 = *(const float4*)(wstft + g);
    float4 v1 = *(const float4*)(wstft + g + 4);
    __hip_bfloat16 t[8];
    t[0] = __float2bfloat16(v0.x); t[1] = __float2bfloat16(v0.y);
    t[2] = __float2bfloat16(v0.z); t[3] = __float2bfloat16(v0.w);
    t[4] = __float2bfloat16(v1.x); t[5] = __float2bfloat16(v1.y);
    t[6] = __float2bfloat16(v1.z); t[7] = __float2bfloat16(v1.w);
    *(uint4*)(wb + g) = *(const uint4*)t;
  } else if (idx < NV1 + NV2 + NV3) {
    int j  = idx - NV1 - NV2;
    int n  = j / (PWC / 8);
    int k0 = (j - n * (PWC / 8)) * 8;
    for (int k = k0; k < k0 + 8; ++k)
      wmt[n * PWC + k] = __float2bfloat16(mf[k * NMEL + n]);
  }
}

// ---------------- p512: power of bin 512 per frame (GEMV pair) ----------------
// grid 32*16; block 256; 64 frames/block (last tile 40). Strided-k mapping to
// dodge the stride-960 LDS bank collision (4-way instead of 16-way).
__launch_bounds__(256, 2)
__global__ void p512_kernel(unsigned char* __restrict__ ws) {
  __shared__ __align__(16) unsigned char xs[62528];
  __shared__ __align__(16) unsigned char wrow[4096];
  const unsigned char* xpadb = ws + XPAD_OFF;
  const unsigned char* wbb   = ws + WB_OFF;
  float* out = (float*)(ws + P512_OFF);

  const int tid  = threadIdx.x;
  const int b    = blockIdx.x >> 4;
  const int tile = blockIdx.x & 15;
  const int t0   = tile * 64;
  const int nf   = (tile == 15) ? 40 : 64;

  const unsigned char* gsrc = xpadb + ((size_t)b * XPADL + (size_t)t0 * HOP) * 2;
  const int nch = ((nf - 1) * HOP + NFFT) * 2 / 16;
  for (int j = tid; j < nch; j += 256)
    *(uint4*)(xs + j * 16) = *(const uint4*)(gsrc + (size_t)j * 16);
  {
    int row = tid >> 7, seg = (tid & 127) * 16;
    *(uint4*)(wrow + tid * 16) = *(const uint4*)(wbb + (size_t)(row ? 1025 : 512) * 2048 + seg);
  }
  __syncthreads();

  const int lane = tid & 63;
  const int wv   = tid >> 6;
  const int kc   = lane & 15;
#pragma unroll
  for (int pass = 0; pass < 4; ++pass) {
    int fr = pass * 16 + wv * 4 + (lane >> 4);
    float dc = 0.f, dsn = 0.f;
    const unsigned char* xp = xs + fr * 960 + kc * 16;
#pragma unroll
    for (int j = 0; j < 8; ++j) {
      ushort8 a  = *(const ushort8*)(xp + j * 256);
      ushort8 uc = *(const ushort8*)(wrow + kc * 16 + j * 256);
      ushort8 us = *(const ushort8*)(wrow + 2048 + kc * 16 + j * 256);
#pragma unroll
      for (int e = 0; e < 8; ++e) {
        float fa = bf2f(a[e]);
        dc  += fa * bf2f(uc[e]);
        dsn += fa * bf2f(us[e]);
      }
    }
#pragma unroll
    for (int d = 1; d < 16; d <<= 1) {
      dc  += __shfl_xor(dc, d);
      dsn += __shfl_xor(dsn, d);
    }
    if (kc == 0 && fr < nf)
      out[(size_t)b * TOUT + t0 + fr] = dc * dc + dsn * dsn;
  }
}

// ---------------- STFT: 256x256, 4-phase counted-vmcnt MFMA GEMM + power ----
// BM=256 frames, BN=256 weight rows (128 bins x {cos,sin}: row n -> bin =
// bin0+(n>>5)*16+(n&15), part=(n>>4)&1). 8 waves (2M x 4N), BK=64, 16 K-tiles,
// dbuf LDS 128 KiB. 4 phases per 2-ktile iteration, 32 MFMA/phase.
// Stage rotation (2 STG = 4 loads / phase), stage >= last-read-phase + 1:
//   ph0: A02(1),A13(1) k2i+1 | ph1: B01(0),B23(0) k2i+2, WAIT_VM(4)
//   ph2: A02(0),A13(0) k2i+2 | ph3: B01(1),B23(1) k2i+3, WAIT_VM(4)
#define STFT_NWG 500
__launch_bounds__(512, 1)
__global__ void stft_kernel(unsigned char* __restrict__ ws) {
  __shared__ __align__(16) unsigned char lds[131072];  // A: cc*32768; B: 65536+cc*32768
  const unsigned char* xpadb = ws + XPAD_OFF;
  const unsigned char* wbb   = ws + WB_OFF;
  __hip_bfloat16* pw = (__hip_bfloat16*)(ws + PW_OFF);

  const int tid  = threadIdx.x;
  const int lane = tid & 63;
  const int w    = tid >> 6;
  const int wm   = w >> 2;
  const int wc   = w & 3;

  // bijective XCD-chunked swizzle (nwg=500: q=62, r=4), n-tile fastest
  const int orig = blockIdx.x;
  const int q8 = STFT_NWG / 8, r8 = STFT_NWG % 8;
  const int xcd = orig & 7;
  const int wg = (xcd < r8 ? xcd * (q8 + 1) : r8 * (q8 + 1) + (xcd - r8) * q8) + (orig >> 3);
  const int bin0 = (wg & 3) * 128;
  const int m0   = (wg >> 2) * 256;

  // staging sources (pre-swizzled col; involution XOR on bits 4..6)
  const int srow = tid >> 3;          // 0..63 row within a 64-row quarter
  const int scol = (tid & 7) << 4;
  const unsigned char *gA0, *gA1, *gA2, *gA3, *gB0, *gB1, *gB2, *gB3;
  {
    int r0 = srow, r1 = 64 + srow, r2 = 128 + srow, r3 = 192 + srow;
    int m, bb, tt;
    m = m0 + r0; bb = m / 1000; tt = m - bb * 1000;
    gA0 = xpadb + ((size_t)bb * XPADL + (size_t)tt * HOP) * 2 + (scol ^ ((r0 & 7) << 4));
    m = m0 + r1; bb = m / 1000; tt = m - bb * 1000;
    gA1 = xpadb + ((size_t)bb * XPADL + (size_t)tt * HOP) * 2 + (scol ^ ((r1 & 7) << 4));
    m = m0 + r2; bb = m / 1000; tt = m - bb * 1000;
    gA2 = xpadb + ((size_t)bb * XPADL + (size_t)tt * HOP) * 2 + (scol ^ ((r2 & 7) << 4));
    m = m0 + r3; bb = m / 1000; tt = m - bb * 1000;
    gA3 = xpadb + ((size_t)bb * XPADL + (size_t)tt * HOP) * 2 + (scol ^ ((r3 & 7) << 4));
#define BROW(r) ((size_t)(bin0 + (((r) >> 5) << 4) + ((r) & 15) + ((((r) >> 4) & 1) * 513)) * 2048)
    gB0 = wbb + BROW(r0) + (scol ^ ((r0 & 7) << 4));
    gB1 = wbb + BROW(r1) + (scol ^ ((r1 & 7) << 4));
    gB2 = wbb + BROW(r2) + (scol ^ ((r2 & 7) << 4));
    gB3 = wbb + BROW(r3) + (scol ^ ((r3 & 7) << 4));
  }

#define LDSA(c, qq) ((void*)(lds + (c) * 32768 + (qq) * 8192 + w * 1024))
#define LDSB(c, qq) ((void*)(lds + 65536 + (c) * 32768 + (qq) * 8192 + w * 1024))
#define STG_B01(c, kb) do { gload16(gB0 + (kb), LDSB(c, 0)); gload16(gB1 + (kb), LDSB(c, 1)); } while (0)
#define STG_B23(c, kb) do { gload16(gB2 + (kb), LDSB(c, 2)); gload16(gB3 + (kb), LDSB(c, 3)); } while (0)
#define STG_A02(c, kb) do { gload16(gA0 + (kb), LDSA(c, 0)); gload16(gA2 + (kb), LDSA(c, 2)); } while (0)
#define STG_A13(c, kb) do { gload16(gA1 + (kb), LDSA(c, 1)); gload16(gA3 + (kb), LDSA(c, 3)); } while (0)

  // hoisted ds_read lane bases (row&7 == lane&7 -> phase-invariant XOR)
  const int xor0 = (((lane >> 4) << 4)) ^ ((lane & 7) << 4);
  const int xor1 = (64 + ((lane >> 4) << 4)) ^ ((lane & 7) << 4);
  const unsigned char* aB0 = lds + wm * 16384 + (lane & 15) * 128 + xor0;
  const unsigned char* aB1 = lds + wm * 16384 + (lane & 15) * 128 + xor1;
  const unsigned char* bB0 = lds + 65536 + wc * 8192 + (lane & 15) * 128 + xor0;
  const unsigned char* bB1 = lds + 65536 + wc * 8192 + (lane & 15) * 128 + xor1;

  f32x4 acc[8][4];
#pragma unroll
  for (int a = 0; a < 8; ++a)
#pragma unroll
    for (int b = 0; b < 4; ++b) acc[a][b] = (f32x4){0.f, 0.f, 0.f, 0.f};

  // prologue: k0 full (8) + k1 B (4) = 12 in flight; retire k0
  STG_B01(0, 0); STG_B23(0, 0); STG_A02(0, 0); STG_A13(0, 0);
  STG_B01(1, 128); STG_B23(1, 128);
  WAIT_VM(4);
  BAR();

  bf16x8 bfr[4][2];
  bf16x8 af[4][2];

#define RD_B(CCOFF)                                                        \
  _Pragma("unroll")                                                        \
  for (int nf = 0; nf < 4; ++nf) {                                         \
    bfr[nf][0] = *(const bf16x8*)(bB0 + (CCOFF) + nf * 2048);              \
    bfr[nf][1] = *(const bf16x8*)(bB1 + (CCOFF) + nf * 2048);              \
  }
#define RD_A(OFF)                                                          \
  _Pragma("unroll")                                                        \
  for (int mi = 0; mi < 4; ++mi) {                                         \
    af[mi][0] = *(const bf16x8*)(aB0 + (OFF) + mi * 2048);                 \
    af[mi][1] = *(const bf16x8*)(aB1 + (OFF) + mi * 2048);                 \
  }
#define DO_MFMA(MBASE)                                                     \
  __builtin_amdgcn_s_setprio(1);                                           \
  _Pragma("unroll")                                                        \
  for (int mi = 0; mi < 4; ++mi)                                           \
    _Pragma("unroll")                                                      \
    for (int nf = 0; nf < 4; ++nf) {                                       \
      acc[(MBASE) + mi][nf] = __builtin_amdgcn_mfma_f32_16x16x32_bf16(     \
          af[mi][0], bfr[nf][0], acc[(MBASE) + mi][nf], 0, 0, 0);          \
      acc[(MBASE) + mi][nf] = __builtin_amdgcn_mfma_f32_16x16x32_bf16(     \
          af[mi][1], bfr[nf][1], acc[(MBASE) + mi][nf], 0, 0, 0);          \
    }                                                                      \
  __builtin_amdgcn_s_setprio(0);

  for (int i = 0; i < 8; ++i) {
    const size_t kOdd = (size_t)(2 * i + 1) * 128;
    const size_t kE2  = (size_t)(2 * i + 2) * 128;
    const size_t kO3  = (size_t)(2 * i + 3) * 128;
    const bool more = (i < 7);
    // ---- ph0: buf0, rows half 0 ----
    RD_B(0); RD_A(0);
    STG_A02(1, kOdd); STG_A13(1, kOdd);
    BAR();
    DO_MFMA(0);
    BAR();
    // ---- ph1: buf0, rows half 1 ----
    RD_A(8192);
    if (more) { STG_B01(0, kE2); STG_B23(0, kE2); WAIT_VM(4); }
    else      { WAIT_VM(0); }
    BAR();
    DO_MFMA(4);
    BAR();
    // ---- ph2: buf1, rows half 0 ----
    RD_B(32768); RD_A(32768);
    if (more) { STG_A02(0, kE2); STG_A13(0, kE2); }
    BAR();
    DO_MFMA(0);
    BAR();
    // ---- ph3: buf1, rows half 1 ----
    RD_A(40960);
    if (more) { STG_B01(1, kO3); STG_B23(1, kO3); WAIT_VM(4); }
    BAR();
    DO_MFMA(4);
    BAR();
  }

  // epilogue: power = cos^2 + sin^2 (nf pairs (0,1),(2,3))
  const int col = lane & 15;
  const int rg  = lane >> 4;
#pragma unroll
  for (int mf_ = 0; mf_ < 8; ++mf_)
#pragma unroll
    for (int g = 0; g < 2; ++g) {
      int bin = bin0 + wc * 32 + g * 16 + col;
#pragma unroll
      for (int rr = 0; rr < 4; ++rr) {
        int m = m0 + wm * 128 + mf_ * 16 + rg * 4 + rr;
        float c = acc[mf_][2 * g][rr];
        float s = acc[mf_][2 * g + 1][rr];
        pw[(size_t)m * PWC + bin] = __float2bfloat16(c * c + s * s);
      }
    }
}

// ---------------- mel GEMM (K=512) + p512 rank-1 + log10 epilogue ----------------
__launch_bounds__(256, 2)
__global__ void mel_kernel(unsigned char* __restrict__ ws, const float* __restrict__ mfp) {
  __shared__ __align__(16) unsigned char sA[128 * 128];
  __shared__ __align__(16) unsigned char sBt[64 * 128];
  const unsigned char* pwb  = ws + PW_OFF;
  const unsigned char* wmtb = ws + WMT_OFF;
  const float* p5 = (const float*)(ws + P512_OFF);
  float* lm = (float*)(ws + LM_OFF);

  const int tid = threadIdx.x;
  const int lane = tid & 63;
  const int wid  = tid >> 6;
  const int m0 = blockIdx.x * 128;

  const int srow = lane >> 3;
  const int kb2  = (lane & 7) << 4;

  const unsigned char* aptr[4];
  unsigned char* aldst[4];
#pragma unroll
  for (int j = 0; j < 4; ++j) {
    int rr = wid * 32 + j * 8 + srow;
    aptr[j] = pwb + (size_t)(m0 + rr) * (PWC * 2) + (kb2 ^ ((rr & 7) << 4));
    aldst[j] = &sA[(wid * 32 + j * 8) * 128];
  }
  const unsigned char* bptr[2];
  unsigned char* bldst[2];
#pragma unroll
  for (int j = 0; j < 2; ++j) {
    int rr = wid * 16 + j * 8 + srow;
    bptr[j] = wmtb + (size_t)rr * (PWC * 2) + (kb2 ^ ((rr & 7) << 4));
    bldst[j] = &sBt[(wid * 16 + j * 8) * 128];
  }

  f32x4 acc[2][4];
#pragma unroll
  for (int mi = 0; mi < 2; ++mi)
#pragma unroll
    for (int fr = 0; fr < 4; ++fr) acc[mi][fr] = (f32x4){0.f, 0.f, 0.f, 0.f};

  for (int kk = 0; kk < PWC; kk += 64) {
    __syncthreads();
#pragma unroll
    for (int j = 0; j < 4; ++j) gload16(aptr[j] + (size_t)kk * 2, aldst[j]);
#pragma unroll
    for (int j = 0; j < 2; ++j) gload16(bptr[j] + (size_t)kk * 2, bldst[j]);
    __syncthreads();
#pragma unroll
    for (int ks = 0; ks < 2; ++ks) {
      const int kby = ks * 64 + ((lane >> 4) << 4);
      bf16x8 af[2], bfr[4];
#pragma unroll
      for (int mi = 0; mi < 2; ++mi) {
        int rr = wid * 32 + mi * 16 + (lane & 15);
        af[mi] = *(const bf16x8*)&sA[rr * 128 + (kby ^ ((rr & 7) << 4))];
      }
#pragma unroll
      for (int fr = 0; fr < 4; ++fr) {
        int rr = fr * 16 + (lane & 15);
        bfr[fr] = *(const bf16x8*)&sBt[rr * 128 + (kby ^ ((rr & 7) << 4))];
      }
#pragma unroll
      for (int mi = 0; mi < 2; ++mi)
#pragma unroll
        for (int fr = 0; fr < 4; ++fr)
          acc[mi][fr] = __builtin_amdgcn_mfma_f32_16x16x32_bf16(af[mi], bfr[fr], acc[mi][fr], 0, 0, 0);
    }
  }

  const int col = lane & 15;
  const int rg  = lane >> 4;
#pragma unroll
  for (int mi = 0; mi < 2; ++mi)
#pragma unroll
    for (int fr = 0; fr < 4; ++fr) {
      int n = fr * 16 + col;
      float f512 = mfp[512 * NMEL + n];
#pragma unroll
      for (int rr = 0; rr < 4; ++rr) {
        int mrow = wid * 32 + mi * 16 + rg * 4 + rr;
        float v = acc[mi][fr][rr] + p5[m0 + mrow] * f512;
        lm[(size_t)(m0 + mrow) * NMEL + n] = 10.0f * log10f(fmaxf(v, 1e-10f));
      }
    }
}

// ---------------- bilinear (time-axis only) interp ----------------
__global__ void interp_kernel(const unsigned char* __restrict__ ws, float* __restrict__ out) {
  const float* lm = (const float*)(ws + LM_OFF);
  int idx = blockIdx.x * blockDim.x + threadIdx.x;
  if (idx >= NBATCH * SPECW * 16) return;
  int m4 = idx & 15;
  int h  = (idx >> 4) & (SPECW - 1);
  int b  = idx >> 14;
  const float scale = (float)(999.0 / 1023.0);
  float pos = (float)h * scale;
  int i0 = (int)floorf(pos);
  if (i0 > TOUT - 1) i0 = TOUT - 1;
  float w = pos - (float)i0;
  int i1 = i0 + 1;
  if (i1 > TOUT - 1) i1 = TOUT - 1;
  const float4* r0 = (const float4*)(lm + ((size_t)b * TOUT + i0) * NMEL);
  const float4* r1 = (const float4*)(lm + ((size_t)b * TOUT + i1) * NMEL);
  float4 a = r0[m4], c = r1[m4];
  float4 o;
  o.x = a.x * (1.0f - w) + c.x * w;
  o.y = a.y * (1.0f - w) + c.y * w;
  o.z = a.z * (1.0f - w) + c.z * w;
  o.w = a.w * (1.0f - w) + c.w * w;
  ((float4*)out)[idx] = o;
}

extern "C" void kernel_launch(void* const* d_in, const int* in_sizes, int n_in,
                              void* d_out, int out_size, void* d_ws, size_t ws_size,
                              hipStream_t stream) {
  (void)in_sizes; (void)n_in; (void)out_size; (void)ws_size;
  const float* wav   = (const float*)d_in[0];
  const float* wstft = (const float*)d_in[1];
  const float* mf    = (const float*)d_in[2];
  unsigned char* ws  = (unsigned char*)d_ws;
  float* out = (float*)d_out;

  const int tot = NV1 + NV2 + NV3;
  prep_kernel<<<(tot + 255) / 256, 256, 0, stream>>>(wav, wstft, mf, ws);
  p512_kernel<<<NBATCH * 16, 256, 0, stream>>>(ws);
  stft_kernel<<<STFT_NWG, 512, 0, stream>>>(ws);
  mel_kernel<<<250, 256, 0, stream>>>(ws, mf);
  interp_kernel<<<(NBATCH * SPECW * 16) / 256, 256, 0, stream>>>(ws, out);
}